// Round 2
// baseline (735.773 us; speedup 1.0000x reference)
//
#include <hip/hip_runtime.h>
#include <math.h>

#define SB 8
#define SS 2048
#define SH 768
#define ALPHA 0.5f
#define TI 32          // q-rows per block
#define JC 16          // k-rows staged per chunk
#define RS4 193        // LDS row stride in float4 (772 floats = 3088 B)
#define NCHUNK 6       // ceil((TI+63)/JC)

// ws float layout:
// 0                    : kw   [SB*SS]  = km * (1/||k||)
// 16384                : qw   [SB*SS]  = qm * (1/||q||)
// 32768                : ksum [SB*SH]
// 38912                : Nk[8], qsum[8], acc[8]

__device__ __forceinline__ float dot4(float4 a, float4 b) {
  return a.x*b.x + a.y*b.y + a.z*b.z + a.w*b.w;
}

__device__ __forceinline__ void g2lds16(const float* g, float* l) {
  __builtin_amdgcn_global_load_lds(
      (const __attribute__((address_space(1))) void*)g,
      (__attribute__((address_space(3))) void*)l, 16, 0, 0);
}

// rows 0..SB*SS-1 : K -> kw ; rows SB*SS.. : Q -> qw
__global__ __launch_bounds__(256) void norm_kernel(
    const float* __restrict__ Q, const float* __restrict__ K,
    const float* __restrict__ qm, const float* __restrict__ km,
    float* __restrict__ qw, float* __restrict__ kw) {
  int lane = threadIdx.x & 63;
  int r2 = blockIdx.x * 4 + (threadIdx.x >> 6);
  bool isQ = r2 >= SB * SS;
  int r = isQ ? r2 - SB * SS : r2;
  const float4* rv = (const float4*)((isQ ? Q : K) + (size_t)r * SH);
  float4 a = rv[lane], b4 = rv[lane + 64], c = rv[lane + 128];
  float s = dot4(a, a) + dot4(b4, b4) + dot4(c, c);
  #pragma unroll
  for (int m = 1; m < 64; m <<= 1) s += __shfl_xor(s, m, 64);
  if (lane == 0) {
    float mask = (isQ ? qm : km)[r];
    (isQ ? qw : kw)[r] = mask / fmaxf(sqrtf(s), 1e-12f);
  }
}

__global__ __launch_bounds__(256) void mask_sums(const float* __restrict__ qm,
                                                 const float* __restrict__ km,
                                                 float* __restrict__ Nk,
                                                 float* __restrict__ qsum) {
  __shared__ float sq[256], sk[256];
  int b = blockIdx.x, t = threadIdx.x;
  float aq = 0.f, ak = 0.f;
  for (int j = t; j < SS; j += 256) { aq += qm[b * SS + j]; ak += km[b * SS + j]; }
  sq[t] = aq; sk[t] = ak; __syncthreads();
  for (int off = 128; off > 0; off >>= 1) {
    if (t < off) { sq[t] += sq[t + off]; sk[t] += sk[t + off]; }
    __syncthreads();
  }
  if (t == 0) { qsum[b] = sq[0]; Nk[b] = sk[0]; }
}

__global__ __launch_bounds__(256) void ksum_kernel(const float* __restrict__ K,
                                                   const float* __restrict__ kw,
                                                   float* __restrict__ ksum) {
  int b = blockIdx.y, jc = blockIdx.x, t = threadIdx.x;
  __shared__ float wsh[64];
  int j0 = jc * 64;
  if (t < 64) wsh[t] = kw[b * SS + j0 + t];
  __syncthreads();
  float a0 = 0.f, a1 = 0.f, a2 = 0.f;
  const float* base = K + ((size_t)b * SS + j0) * SH;
  for (int jj = 0; jj < 64; jj++) {
    float wv = wsh[jj];
    if (wv != 0.0f) {
      const float* rp = base + (size_t)jj * SH;
      a0 += rp[t] * wv;
      a1 += rp[t + 256] * wv;
      a2 += rp[t + 512] * wv;
    }
  }
  atomicAdd(&ksum[b * SH + t], a0);
  atomicAdd(&ksum[b * SH + t + 256], a1);
  atomicAdd(&ksum[b * SH + t + 512], a2);
}

__global__ __launch_bounds__(512, 4) void band_kernel(
    const float* __restrict__ Q, const float* __restrict__ K,
    const float* __restrict__ temp,
    const float* __restrict__ qw, const float* __restrict__ kw,
    const float* __restrict__ ksum, const float* __restrict__ Nk,
    float* __restrict__ acc) {
  __shared__ float4 kb[JC * RS4];     // 49408 B
  __shared__ float tab_s[64];
  __shared__ float kwc[JC];
  __shared__ float wsum[8];
  int tid = threadIdx.x;
  int w = tid >> 6, lane = tid & 63, g = lane >> 4, u = lane & 15;
  int blk = blockIdx.x;
  int b = blk >> 6;                    // grid = 8 * 64
  int i0 = (blk & 63) * TI;
  if (tid < 64) {
    float invt = 1.0f / temp[0];
    tab_s[tid] = __expf(-ALPHA * fabsf((float)(tid - 31))) * invt;
  }
  float anum[4] = {0, 0, 0, 0}, aden[4] = {0, 0, 0, 0}, d0v[4] = {0, 0, 0, 0};
  const float* Kb = K + (size_t)b * SS * SH;
  const float* kwb = kw + b * SS;
  float* ldsf = (float*)kb;

  for (int c = 0; c < NCHUNK; ++c) {
    int jlo = i0 - 31 + JC * c;
    __syncthreads();   // previous chunk's compute done before overwriting LDS
    // stage 16 K rows (3 KB each) via async global->LDS, 48 wave-issues total
    #pragma unroll
    for (int q = 0; q < 6; ++q) {
      int idx = w * 6 + q;           // 0..47
      int rrow = idx / 3, part = idx % 3;
      int j = jlo + rrow;
      int jcl = min(max(j, 0), SS - 1);
      const float* gsrc = Kb + (size_t)jcl * SH + part * 256 + lane * 4;
      float* dst = ldsf + rrow * (RS4 * 4) + part * 256;
      g2lds16(gsrc, dst);
    }
    if (tid < JC) {
      int j = jlo + tid;
      kwc[tid] = (j >= 0 && j < SS) ? kwb[j] : 0.0f;
    }
    __syncthreads();   // staging drained (vmcnt(0) before barrier)

    #pragma unroll
    for (int p = 0; p < 4; ++p) {
      int i = i0 + w * 4 + p;
      int r = b * SS + i;
      float qwv = qw[r];
      if (qwv == 0.0f) continue;       // wave-uniform
      const float4* qr = (const float4*)(Q + (size_t)r * SH);
      float4 qf[12];
      #pragma unroll
      for (int m = 0; m < 12; ++m) qf[m] = qr[u + 16 * m];
      if (c == 0) {
        // far-field rank-1 term: q . ksum, split m-range across g
        const float4* ks = (const float4*)(ksum + b * SH);
        float s = 0.f;
        #pragma unroll
        for (int mm = 0; mm < 3; ++mm) {
          int m = 3 * g + mm;
          s += dot4(qf[m], ks[u + 16 * m]);
        }
        d0v[p] = s;
      }
      int jA = max(i - 31, max(jlo, 0));
      int jB = min(i + 32, min(jlo + JC - 1, SS - 1));
      for (int jb = jA; jb <= jB; jb += 4) {
        int j = jb + g;
        bool val = j <= jB;
        int row = (val ? j : jB) - jlo;          // 0..15
        const float4* kr = kb + row * RS4;
        float d = 0.f;
        #pragma unroll
        for (int m = 0; m < 12; ++m) d += dot4(qf[m], kr[u + 16 * m]);
        d += __shfl_xor(d, 1, 64); d += __shfl_xor(d, 2, 64);
        d += __shfl_xor(d, 4, 64); d += __shfl_xor(d, 8, 64);
        float wfj = val ? kwc[row] : 0.0f;
        float sv = d * qwv * wfj;                 // masked sim value
        float lv = sv * tab_s[val ? (j - i + 31) : 0];
        float ev = __expf(lv) - 1.0f;             // exp(logit) - 1
        anum[p] += ev * sv;
        aden[p] += ev;
      }
    }
  }

  float wacc = 0.f;
  #pragma unroll
  for (int p = 0; p < 4; ++p) {
    int i = i0 + w * 4 + p;
    int r = b * SS + i;
    float qwv = qw[r];
    float d0 = d0v[p];
    #pragma unroll
    for (int m = 1; m < 64; m <<= 1) d0 += __shfl_xor(d0, m, 64);
    float an = anum[p]; an += __shfl_xor(an, 16, 64); an += __shfl_xor(an, 32, 64);
    float ad = aden[p]; ad += __shfl_xor(ad, 16, 64); ad += __shfl_xor(ad, 32, 64);
    float sc = (qwv == 0.0f) ? 0.0f : (qwv * d0 + an) / (Nk[b] + ad);
    wacc += sc;
  }
  if (lane == 0) wsum[w] = wacc;
  __syncthreads();
  if (tid == 0) {
    float s = 0.f;
    #pragma unroll
    for (int x = 0; x < 8; ++x) s += wsum[x];
    atomicAdd(&acc[b], s);
  }
}

__global__ void finalize_kernel(const float* __restrict__ acc,
                                const float* __restrict__ qsum,
                                float* __restrict__ out) {
  int b = threadIdx.x;
  if (b < SB) out[b] = acc[b] / fmaxf(qsum[b], 1.0f);
}

extern "C" void kernel_launch(void* const* d_in, const int* in_sizes, int n_in,
                              void* d_out, int out_size, void* d_ws, size_t ws_size,
                              hipStream_t stream) {
  const float* Q    = (const float*)d_in[0];
  const float* K    = (const float*)d_in[1];
  const float* qm   = (const float*)d_in[2];
  const float* km   = (const float*)d_in[3];
  const float* temp = (const float*)d_in[4];
  float* ws   = (float*)d_ws;
  float* kw   = ws;
  float* qwv  = ws + SB * SS;
  float* ksum = ws + 2 * SB * SS;
  float* Nk   = ksum + SB * SH;
  float* qsum = Nk + 8;
  float* accb = qsum + 8;
  float* outp = (float*)d_out;

  hipMemsetAsync(ksum, 0, (SB * SH + 24) * sizeof(float), stream);

  norm_kernel<<<2 * SB * SS / 4, 256, 0, stream>>>(Q, K, qm, km, qwv, kw);
  mask_sums<<<SB, 256, 0, stream>>>(qm, km, Nk, qsum);
  ksum_kernel<<<dim3(32, SB), 256, 0, stream>>>(K, kw, ksum);
  band_kernel<<<SB * (SS / TI), 512, 0, stream>>>(Q, K, temp, qwv, kw, ksum, Nk, accb);
  finalize_kernel<<<1, 64, 0, stream>>>(accb, qsum, outp);
}

// Round 3
// 273.745 us; speedup vs baseline: 2.6878x; 2.6878x over previous
//
#include <hip/hip_runtime.h>
#include <math.h>

#define SB 8
#define SS 2048
#define SH 768
#define ALPHA 0.5f
#define WV 8           // waves per block = q-rows per block
#define JC 16          // k-rows staged per chunk
#define RS4 193        // LDS row stride in float4 (772 floats = 3088 B)
#define NCHUNK 5       // covers [i0-31, i0+48] >= band union [i0-31, i0+39]

// ws float layout:
// 0                    : kw   [SB*SS]  = km * (1/||k||)
// 16384                : qw   [SB*SS]  = qm * (1/||q||)
// 32768                : ksum [SB*SH]
// 38912                : Nk[8], qsum[8], acc[8]

__device__ __forceinline__ float dot4(float4 a, float4 b) {
  return a.x*b.x + a.y*b.y + a.z*b.z + a.w*b.w;
}

__device__ __forceinline__ void g2lds16(const float* g, float* l) {
  __builtin_amdgcn_global_load_lds(
      (const __attribute__((address_space(1))) void*)g,
      (__attribute__((address_space(3))) void*)l, 16, 0, 0);
}

__global__ __launch_bounds__(256) void norm_kernel(
    const float* __restrict__ Q, const float* __restrict__ K,
    const float* __restrict__ qm, const float* __restrict__ km,
    float* __restrict__ qw, float* __restrict__ kw) {
  int lane = threadIdx.x & 63;
  int r2 = blockIdx.x * 4 + (threadIdx.x >> 6);
  bool isQ = r2 >= SB * SS;
  int r = isQ ? r2 - SB * SS : r2;
  const float4* rv = (const float4*)((isQ ? Q : K) + (size_t)r * SH);
  float4 a = rv[lane], b4 = rv[lane + 64], c = rv[lane + 128];
  float s = dot4(a, a) + dot4(b4, b4) + dot4(c, c);
  #pragma unroll
  for (int m = 1; m < 64; m <<= 1) s += __shfl_xor(s, m, 64);
  if (lane == 0) {
    float mask = (isQ ? qm : km)[r];
    (isQ ? qw : kw)[r] = mask / fmaxf(sqrtf(s), 1e-12f);
  }
}

__global__ __launch_bounds__(256) void mask_sums(const float* __restrict__ qm,
                                                 const float* __restrict__ km,
                                                 float* __restrict__ Nk,
                                                 float* __restrict__ qsum) {
  __shared__ float sq[256], sk[256];
  int b = blockIdx.x, t = threadIdx.x;
  float aq = 0.f, ak = 0.f;
  for (int j = t; j < SS; j += 256) { aq += qm[b * SS + j]; ak += km[b * SS + j]; }
  sq[t] = aq; sk[t] = ak; __syncthreads();
  for (int off = 128; off > 0; off >>= 1) {
    if (t < off) { sq[t] += sq[t + off]; sk[t] += sk[t + off]; }
    __syncthreads();
  }
  if (t == 0) { qsum[b] = sq[0]; Nk[b] = sk[0]; }
}

__global__ __launch_bounds__(256) void ksum_kernel(const float* __restrict__ K,
                                                   const float* __restrict__ kw,
                                                   float* __restrict__ ksum) {
  int b = blockIdx.y, jc = blockIdx.x, t = threadIdx.x;
  __shared__ float wsh[64];
  int j0 = jc * 64;
  if (t < 64) wsh[t] = kw[b * SS + j0 + t];
  __syncthreads();
  float a0 = 0.f, a1 = 0.f, a2 = 0.f;
  const float* base = K + ((size_t)b * SS + j0) * SH;
  for (int jj = 0; jj < 64; jj++) {
    float wv = wsh[jj];
    if (wv != 0.0f) {
      const float* rp = base + (size_t)jj * SH;
      a0 += rp[t] * wv;
      a1 += rp[t + 256] * wv;
      a2 += rp[t + 512] * wv;
    }
  }
  atomicAdd(&ksum[b * SH + t], a0);
  atomicAdd(&ksum[b * SH + t + 256], a1);
  atomicAdd(&ksum[b * SH + t + 512], a2);
}

// One wave per q-row i. qf (48 VGPRs, pre-scaled by qw) lives for the whole
// kernel; accumulators are 3 scalars -> no spill pressure.
__global__ __launch_bounds__(512, 4) void band_kernel(
    const float* __restrict__ Q, const float* __restrict__ K,
    const float* __restrict__ temp,
    const float* __restrict__ qw, const float* __restrict__ kw,
    const float* __restrict__ ksum, const float* __restrict__ Nk,
    float* __restrict__ acc) {
  __shared__ float4 kb[JC * RS4];     // 49408 B
  __shared__ float tab_s[64];
  __shared__ float kwc[JC];
  __shared__ float wsum[WV];
  int tid = threadIdx.x;
  int w = tid >> 6, lane = tid & 63, g = lane >> 4, u = lane & 15;
  int blk = blockIdx.x;
  int b = blk >> 8;                    // grid = 8 * 256
  int i0 = (blk & 255) * WV;
  int i = i0 + w;
  int r = b * SS + i;
  if (tid < 64) {
    float invt = 1.0f / temp[0];
    tab_s[tid] = __expf(-ALPHA * fabsf((float)(tid - 31))) * invt;
  }
  // load q fragment once, fold in qw (qm/||q||)
  float qwv = qw[r];
  const float4* qr = (const float4*)(Q + (size_t)r * SH);
  float4 qf[12];
  #pragma unroll
  for (int m = 0; m < 12; ++m) {
    float4 v = qr[u + 16 * m];
    v.x *= qwv; v.y *= qwv; v.z *= qwv; v.w *= qwv;
    qf[m] = v;
  }
  // far-field rank-1 term (partial; reduced at the end)
  const float4* ks = (const float4*)(ksum + (size_t)b * SH);
  float d0 = 0.f;
  #pragma unroll
  for (int mm = 0; mm < 3; ++mm) {
    int m = 3 * g + mm;
    d0 += dot4(qf[m], ks[u + 16 * m]);
  }

  float an = 0.f, ad = 0.f;
  const float* Kb = K + (size_t)b * SS * SH;
  const float* kwb = kw + b * SS;
  float* ldsf = (float*)kb;

  for (int c = 0; c < NCHUNK; ++c) {
    int jlo = i0 - 31 + JC * c;
    __syncthreads();                   // LDS reuse guard
    #pragma unroll
    for (int q = 0; q < 6; ++q) {      // 8 waves x 6 = 48 issues = 16 rows x 3 parts
      int rrow = 2 * w + (q >= 3 ? 1 : 0);
      int part = q - (q >= 3 ? 3 : 0);
      int j = jlo + rrow;
      int jcl = min(max(j, 0), SS - 1);
      const float* gsrc = Kb + (size_t)jcl * SH + part * 256 + lane * 4;
      float* dst = ldsf + rrow * (RS4 * 4) + part * 256;
      g2lds16(gsrc, dst);
    }
    if (tid < JC) {
      int j = jlo + tid;
      kwc[tid] = (j >= 0 && j < SS) ? kwb[j] : 0.0f;
    }
    __syncthreads();                   // staging drained

    int jA = max(max(i - 31, jlo), 0);
    int jB = min(min(i + 32, jlo + JC - 1), SS - 1);
    for (int jb = jA; jb <= jB; jb += 4) {
      int j = jb + g;
      bool val = j <= jB;
      int row = (val ? j : jA) - jlo;  // in [0, JC)
      const float4* kr = kb + row * RS4;
      float d = 0.f;
      #pragma unroll
      for (int m = 0; m < 12; ++m) d += dot4(qf[m], kr[u + 16 * m]);
      d += __shfl_xor(d, 1, 64); d += __shfl_xor(d, 2, 64);
      d += __shfl_xor(d, 4, 64); d += __shfl_xor(d, 8, 64);
      float wfj = val ? kwc[row] : 0.0f;
      float sv = d * wfj;                       // masked sim (incl. qm/norms)
      float lv = sv * tab_s[val ? (j - i + 31) : 0];
      float ev = __expf(lv) - 1.0f;
      an += ev * sv;
      ad += ev;
    }
  }

  #pragma unroll
  for (int m = 1; m < 64; m <<= 1) d0 += __shfl_xor(d0, m, 64);
  an += __shfl_xor(an, 16, 64); an += __shfl_xor(an, 32, 64);
  ad += __shfl_xor(ad, 16, 64); ad += __shfl_xor(ad, 32, 64);
  float sc = (d0 + an) / (Nk[b] + ad);          // qwv==0 -> 0/(Nk) = 0
  if (lane == 0) wsum[w] = sc;
  __syncthreads();
  if (tid == 0) {
    float s = 0.f;
    #pragma unroll
    for (int x = 0; x < WV; ++x) s += wsum[x];
    atomicAdd(&acc[b], s);
  }
}

__global__ void finalize_kernel(const float* __restrict__ acc,
                                const float* __restrict__ qsum,
                                float* __restrict__ out) {
  int b = threadIdx.x;
  if (b < SB) out[b] = acc[b] / fmaxf(qsum[b], 1.0f);
}

extern "C" void kernel_launch(void* const* d_in, const int* in_sizes, int n_in,
                              void* d_out, int out_size, void* d_ws, size_t ws_size,
                              hipStream_t stream) {
  const float* Q    = (const float*)d_in[0];
  const float* K    = (const float*)d_in[1];
  const float* qm   = (const float*)d_in[2];
  const float* km   = (const float*)d_in[3];
  const float* temp = (const float*)d_in[4];
  float* ws   = (float*)d_ws;
  float* kw   = ws;
  float* qwv  = ws + SB * SS;
  float* ksum = ws + 2 * SB * SS;
  float* Nk   = ksum + SB * SH;
  float* qsum = Nk + 8;
  float* accb = qsum + 8;
  float* outp = (float*)d_out;

  hipMemsetAsync(ksum, 0, (SB * SH + 24) * sizeof(float), stream);

  norm_kernel<<<2 * SB * SS / 4, 256, 0, stream>>>(Q, K, qm, km, qwv, kw);
  mask_sums<<<SB, 256, 0, stream>>>(qm, km, Nk, qsum);
  ksum_kernel<<<dim3(32, SB), 256, 0, stream>>>(K, kw, ksum);
  band_kernel<<<SB * (SS / WV), 512, 0, stream>>>(Q, K, temp, qwv, kw, ksum, Nk, accb);
  finalize_kernel<<<1, 64, 0, stream>>>(accb, qsum, outp);
}